// Round 1
// baseline (543.412 us; speedup 1.0000x reference)
//
#include <hip/hip_runtime.h>

#define N_DRUG 10000
#define N_DIS  10000
#define IN_UNITS 256
#define H1 128
#define H2 64

// ---------------- K1: node projections ----------------
// drug_proj[r] = drug_feat[r] @ W1[0:256,:]          (10000 x 128)
// dis_proj[r]  = dis_feat[r]  @ W1[256:512,:] + b1   (10000 x 128)
// grid.x = 2 * (rows/16); block 256
__global__ __launch_bounds__(256) void proj_kernel(
    const float* __restrict__ drug_feat, const float* __restrict__ dis_feat,
    const float* __restrict__ W1, const float* __restrict__ b1,
    float* __restrict__ drug_proj, float* __restrict__ dis_proj,
    int blocks_per_side)
{
    __shared__ float feats[16 * 257];   // 16 rows x 256, padded to 257
    __shared__ float w1s[64 * 128];     // one K-chunk of W1

    int b = blockIdx.x;
    bool isDis = b >= blocks_per_side;
    int r0 = (isDis ? b - blocks_per_side : b) * 16;
    const float* feat  = isDis ? dis_feat : drug_feat;
    const float* w1base = W1 + (isDis ? (size_t)IN_UNITS * H1 : 0);
    float* outp = isDis ? dis_proj : drug_proj;
    int t = threadIdx.x;

    // stage 16 feature rows (contiguous 16KB)
    {
        const float4* src = (const float4*)(feat + (size_t)r0 * IN_UNITS);
        #pragma unroll
        for (int i = 0; i < 4; ++i) {
            int f4 = t + i * 256;          // float4 index in [0,1024)
            float4 v = src[f4];
            int f = f4 * 4;
            int r = f >> 8, k = f & 255;
            float* dstp = &feats[r * 257 + k];
            dstp[0] = v.x; dstp[1] = v.y; dstp[2] = v.z; dstp[3] = v.w;
        }
    }

    float acc0[4] = {0.f, 0.f, 0.f, 0.f};
    float acc1[4] = {0.f, 0.f, 0.f, 0.f};
    int rr = (t >> 5) * 2;        // 2 rows per thread
    int c0 = (t & 31) * 4;        // 4 cols per thread

    for (int k0 = 0; k0 < IN_UNITS; k0 += 64) {
        __syncthreads();
        {   // stage W1 chunk [64][128] (contiguous 32KB)
            const float4* src = (const float4*)(w1base + (size_t)k0 * H1);
            float4* dst = (float4*)w1s;
            #pragma unroll
            for (int i = 0; i < 8; ++i) dst[t + i * 256] = src[t + i * 256];
        }
        __syncthreads();
        #pragma unroll 8
        for (int k = 0; k < 64; ++k) {
            float f0 = feats[rr * 257 + k0 + k];
            float f1 = feats[(rr + 1) * 257 + k0 + k];
            const float* wp = &w1s[k * 128 + c0];
            #pragma unroll
            for (int i = 0; i < 4; ++i) {
                float w = wp[i];
                acc0[i] += f0 * w;
                acc1[i] += f1 * w;
            }
        }
    }

    #pragma unroll
    for (int i = 0; i < 4; ++i) {
        float v0 = acc0[i], v1 = acc1[i];
        if (isDis) { float bb = b1[c0 + i]; v0 += bb; v1 += bb; }
        outp[(size_t)(r0 + rr)     * H1 + c0 + i] = v0;
        outp[(size_t)(r0 + rr + 1) * H1 + c0 + i] = v1;
    }
}

// ---------------- K2: per-edge MLP ----------------
// 64 edges per block, 256 threads (4 waves, 16 edges/wave)
__global__ __launch_bounds__(256) void edge_kernel(
    const float* __restrict__ drug_proj, const float* __restrict__ dis_proj,
    const int* __restrict__ src_idx, const int* __restrict__ dst_idx,
    const float* __restrict__ W2, const float* __restrict__ b2,
    const float* __restrict__ W3, const float* __restrict__ b3,
    float* __restrict__ out, int n_edges)
{
    __shared__ float4 h1t[32][64];      // [k/4][edge] : h1[e][4k..4k+3], 32KB
    __shared__ float  w2s[H1 * H2];     // row-major W2, 32KB

    int t = threadIdx.x;

    // stage W2 (contiguous 32KB)
    {
        const float4* src = (const float4*)W2;
        float4* dst = (float4*)w2s;
        #pragma unroll
        for (int i = 0; i < 8; ++i) dst[t + i * 256] = src[t + i * 256];
    }

    long e0 = (long)blockIdx.x * 64;

    // phase 1: h1 = relu(drug_proj[s] + dis_proj[d])  -> LDS
    {
        int el = t >> 2, g = t & 3;     // edge-local, k-subgroup
        long e = e0 + el;
        if (e >= n_edges) e = n_edges - 1;
        int s = src_idx[e];
        int d = dst_idx[e];
        const float* dp = drug_proj + (size_t)s * H1;
        const float* pp = dis_proj + (size_t)d * H1;
        #pragma unroll
        for (int i = 0; i < 8; ++i) {
            int k = i * 16 + g * 4;     // 4 consecutive lanes cover 64B
            float4 a = *(const float4*)(dp + k);
            float4 bq = *(const float4*)(pp + k);
            float4 h;
            h.x = fmaxf(a.x + bq.x, 0.f);
            h.y = fmaxf(a.y + bq.y, 0.f);
            h.z = fmaxf(a.z + bq.z, 0.f);
            h.w = fmaxf(a.w + bq.w, 0.f);
            h1t[i * 4 + g][el] = h;
        }
    }
    __syncthreads();

    // phase 2: h2[e][lane] = sum_k h1[e][k] * W2[k][lane]
    int wave = t >> 6, lane = t & 63;
    int ebase = wave * 16;
    float acc[16];
    #pragma unroll
    for (int e = 0; e < 16; ++e) acc[e] = 0.f;

    const float* w2p = &w2s[lane];
    #pragma unroll 2
    for (int kk = 0; kk < 32; ++kk) {
        float w0 = w2p[(kk * 4 + 0) * 64];
        float w1v = w2p[(kk * 4 + 1) * 64];
        float w2v = w2p[(kk * 4 + 2) * 64];
        float w3v = w2p[(kk * 4 + 3) * 64];
        #pragma unroll
        for (int e = 0; e < 16; ++e) {
            float4 h = h1t[kk][ebase + e];   // uniform-address broadcast
            acc[e] += h.x * w0;
            acc[e] += h.y * w1v;
            acc[e] += h.z * w2v;
            acc[e] += h.w * w3v;
        }
    }

    // phase 3: relu(h2 + b2) . W3 + b3, butterfly reduce over 64 lanes
    float b2j = b2[lane];
    float w3j = W3[lane];
    float b3v = b3[0];
    float s[16];
    #pragma unroll
    for (int e = 0; e < 16; ++e) {
        float h = fmaxf(acc[e] + b2j, 0.f);
        s[e] = h * w3j;
    }
    #pragma unroll
    for (int off = 32; off >= 1; off >>= 1) {
        #pragma unroll
        for (int e = 0; e < 16; ++e)
            s[e] += __shfl_xor(s[e], off, 64);
    }
    if (lane == 0) {
        #pragma unroll
        for (int e = 0; e < 16; ++e) {
            long idx = e0 + ebase + e;
            if (idx < n_edges) out[idx] = s[e] + b3v;
        }
    }
}

extern "C" void kernel_launch(void* const* d_in, const int* in_sizes, int n_in,
                              void* d_out, int out_size, void* d_ws, size_t ws_size,
                              hipStream_t stream) {
    const float* drug_feat = (const float*)d_in[0];
    const float* dis_feat  = (const float*)d_in[1];
    const int*   src_idx   = (const int*)d_in[2];
    const int*   dst_idx   = (const int*)d_in[3];
    const float* W1 = (const float*)d_in[4];
    const float* b1 = (const float*)d_in[5];
    const float* W2 = (const float*)d_in[6];
    const float* b2 = (const float*)d_in[7];
    const float* W3 = (const float*)d_in[8];
    const float* b3 = (const float*)d_in[9];
    float* out = (float*)d_out;

    int n_edges = in_sizes[2];
    int n_drug = in_sizes[0] / IN_UNITS;
    int n_dis  = in_sizes[1] / IN_UNITS;

    float* drug_proj = (float*)d_ws;
    float* dis_proj  = drug_proj + (size_t)n_drug * H1;

    int blocks_per_side = (n_drug + 15) / 16;   // 625
    int proj_blocks = 2 * blocks_per_side;
    proj_kernel<<<proj_blocks, 256, 0, stream>>>(
        drug_feat, dis_feat, W1, b1, drug_proj, dis_proj, blocks_per_side);

    int edge_blocks = (n_edges + 63) / 64;      // 15625
    edge_kernel<<<edge_blocks, 256, 0, stream>>>(
        drug_proj, dis_proj, src_idx, dst_idx, W2, b2, W3, b3, out, n_edges);
}

// Round 2
// 243.412 us; speedup vs baseline: 2.2325x; 2.2325x over previous
//
#include <hip/hip_runtime.h>

#define IN_UNITS 256
#define H1 128
#define H2 64

typedef __attribute__((ext_vector_type(8))) short bf16x8;
typedef __attribute__((ext_vector_type(4))) float f32x4;

static __device__ __forceinline__ short f2bf(float x) {
    union { float f; unsigned u; } c; c.f = x;
    unsigned r = (c.u + 0x7fffu + ((c.u >> 16) & 1u)) >> 16;
    return (short)r;
}

// ---------------- K0: pack W2 into bf16 MFMA B-fragment lane order ----------------
// frag f = ks*4+nt; lane l, elem j holds W2[ks*32 + (l>>4)*8 + j][nt*16 + (l&15)]
// stored as w2pack[f*64 + l] (uint4 = 8 bf16)
__global__ __launch_bounds__(256) void pack_w2_kernel(
    const float* __restrict__ W2, uint4* __restrict__ w2pack)
{
    int t = threadIdx.x;
    #pragma unroll
    for (int i = 0; i < 4; ++i) {
        int item = t + i * 256;          // 0..1023
        int f = item >> 6, l = item & 63;
        int ks = f >> 2, nt = f & 3;
        int row0 = ks * 32 + (l >> 4) * 8;
        int col  = nt * 16 + (l & 15);
        unsigned short h[8];
        #pragma unroll
        for (int j = 0; j < 8; ++j)
            h[j] = (unsigned short)f2bf(W2[(size_t)(row0 + j) * H2 + col]);
        uint4 v;
        v.x = (unsigned)h[0] | ((unsigned)h[1] << 16);
        v.y = (unsigned)h[2] | ((unsigned)h[3] << 16);
        v.z = (unsigned)h[4] | ((unsigned)h[5] << 16);
        v.w = (unsigned)h[6] | ((unsigned)h[7] << 16);
        w2pack[item] = v;
    }
}

// ---------------- K1: node projections (fp32, unchanged from round 1) ----------------
__global__ __launch_bounds__(256) void proj_kernel(
    const float* __restrict__ drug_feat, const float* __restrict__ dis_feat,
    const float* __restrict__ W1, const float* __restrict__ b1,
    float* __restrict__ drug_proj, float* __restrict__ dis_proj,
    int blocks_per_side)
{
    __shared__ float feats[16 * 257];
    __shared__ float w1s[64 * 128];

    int b = blockIdx.x;
    bool isDis = b >= blocks_per_side;
    int r0 = (isDis ? b - blocks_per_side : b) * 16;
    const float* feat  = isDis ? dis_feat : drug_feat;
    const float* w1base = W1 + (isDis ? (size_t)IN_UNITS * H1 : 0);
    float* outp = isDis ? dis_proj : drug_proj;
    int t = threadIdx.x;

    {
        const float4* src = (const float4*)(feat + (size_t)r0 * IN_UNITS);
        #pragma unroll
        for (int i = 0; i < 4; ++i) {
            int f4 = t + i * 256;
            float4 v = src[f4];
            int f = f4 * 4;
            int r = f >> 8, k = f & 255;
            float* dstp = &feats[r * 257 + k];
            dstp[0] = v.x; dstp[1] = v.y; dstp[2] = v.z; dstp[3] = v.w;
        }
    }

    float acc0[4] = {0.f, 0.f, 0.f, 0.f};
    float acc1[4] = {0.f, 0.f, 0.f, 0.f};
    int rr = (t >> 5) * 2;
    int c0 = (t & 31) * 4;

    for (int k0 = 0; k0 < IN_UNITS; k0 += 64) {
        __syncthreads();
        {
            const float4* src = (const float4*)(w1base + (size_t)k0 * H1);
            float4* dst = (float4*)w1s;
            #pragma unroll
            for (int i = 0; i < 8; ++i) dst[t + i * 256] = src[t + i * 256];
        }
        __syncthreads();
        #pragma unroll 8
        for (int k = 0; k < 64; ++k) {
            float f0 = feats[rr * 257 + k0 + k];
            float f1 = feats[(rr + 1) * 257 + k0 + k];
            const float* wp = &w1s[k * 128 + c0];
            #pragma unroll
            for (int i = 0; i < 4; ++i) {
                float w = wp[i];
                acc0[i] += f0 * w;
                acc1[i] += f1 * w;
            }
        }
    }

    #pragma unroll
    for (int i = 0; i < 4; ++i) {
        float v0 = acc0[i], v1 = acc1[i];
        if (isDis) { float bb = b1[c0 + i]; v0 += bb; v1 += bb; }
        outp[(size_t)(r0 + rr)     * H1 + c0 + i] = v0;
        outp[(size_t)(r0 + rr + 1) * H1 + c0 + i] = v1;
    }
}

// ---------------- K2: per-edge MLP via MFMA, zero LDS ----------------
// 256 threads = 4 waves; 32 edges/wave (2 M-tiles of 16); 128 edges/block
__global__ __launch_bounds__(256) void edge_kernel(
    const float* __restrict__ drug_proj, const float* __restrict__ dis_proj,
    const int* __restrict__ src_idx, const int* __restrict__ dst_idx,
    const uint4* __restrict__ w2pack, const float* __restrict__ b2,
    const float* __restrict__ W3, const float* __restrict__ b3,
    float* __restrict__ out, int n_edges)
{
    int lane = threadIdx.x & 63;
    int wave = threadIdx.x >> 6;
    long e0 = ((long)blockIdx.x * 4 + wave) * 32;
    if (e0 >= n_edges) return;

    // B fragments: all of W2, kept in VGPRs (16 x dwordx4, coalesced, L2-hit)
    bf16x8 bfrag[4][4];   // [ks][nt]
    {
        const uint4* p = w2pack + lane;
        #pragma unroll
        for (int ks = 0; ks < 4; ++ks)
            #pragma unroll
            for (int nt = 0; nt < 4; ++nt) {
                uint4 v = p[(size_t)(ks * 4 + nt) * 64];
                union { uint4 u; bf16x8 b; } cv; cv.u = v;
                bfrag[ks][nt] = cv.b;
            }
    }

    // epilogue constants
    float b2v[4], w3v[4];
    #pragma unroll
    for (int nt = 0; nt < 4; ++nt) {
        int col = (lane & 15) + nt * 16;
        b2v[nt] = b2[col];
        w3v[nt] = W3[col];
    }
    float b3v = b3[0];

    f32x4 acc[2][4];   // [mt][nt]
    #pragma unroll
    for (int mt = 0; mt < 2; ++mt)
        #pragma unroll
        for (int nt = 0; nt < 4; ++nt)
            acc[mt][nt] = (f32x4){0.f, 0.f, 0.f, 0.f};

    int kb = (lane >> 4) * 8;   // this lane's k-offset within a 32-wide K-step

    #pragma unroll
    for (int mt = 0; mt < 2; ++mt) {
        long em = e0 + mt * 16 + (lane & 15);
        if (em >= n_edges) em = n_edges - 1;
        int s = src_idx[em];
        int d = dst_idx[em];
        const float* dp = drug_proj + (size_t)s * H1;
        const float* pp = dis_proj  + (size_t)d * H1;

        bf16x8 afrag[4];
        #pragma unroll
        for (int ks = 0; ks < 4; ++ks) {
            int k0 = ks * 32 + kb;
            float4 a0 = *(const float4*)(dp + k0);
            float4 a1 = *(const float4*)(dp + k0 + 4);
            float4 c0 = *(const float4*)(pp + k0);
            float4 c1 = *(const float4*)(pp + k0 + 4);
            float h[8];
            h[0] = fmaxf(a0.x + c0.x, 0.f);
            h[1] = fmaxf(a0.y + c0.y, 0.f);
            h[2] = fmaxf(a0.z + c0.z, 0.f);
            h[3] = fmaxf(a0.w + c0.w, 0.f);
            h[4] = fmaxf(a1.x + c1.x, 0.f);
            h[5] = fmaxf(a1.y + c1.y, 0.f);
            h[6] = fmaxf(a1.z + c1.z, 0.f);
            h[7] = fmaxf(a1.w + c1.w, 0.f);
            bf16x8 af;
            #pragma unroll
            for (int j = 0; j < 8; ++j) af[j] = f2bf(h[j]);
            afrag[ks] = af;
        }

        #pragma unroll
        for (int ks = 0; ks < 4; ++ks)
            #pragma unroll
            for (int nt = 0; nt < 4; ++nt)
                acc[mt][nt] = __builtin_amdgcn_mfma_f32_16x16x32_bf16(
                    afrag[ks], bfrag[ks][nt], acc[mt][nt], 0, 0, 0);
    }

    // epilogue: out[e] = relu(h2 + b2) . W3 + b3
    // acc[mt][nt][r] = h2[edge = mt*16 + (lane>>4)*4 + r][col = (lane&15) + 16*nt]
    #pragma unroll
    for (int mt = 0; mt < 2; ++mt) {
        float part[4];
        #pragma unroll
        for (int r = 0; r < 4; ++r) {
            float p = 0.f;
            #pragma unroll
            for (int nt = 0; nt < 4; ++nt)
                p += fmaxf(acc[mt][nt][r] + b2v[nt], 0.f) * w3v[nt];
            part[r] = p;
        }
        #pragma unroll
        for (int off = 1; off <= 8; off <<= 1)
            #pragma unroll
            for (int r = 0; r < 4; ++r)
                part[r] += __shfl_xor(part[r], off, 64);
        if ((lane & 15) == 0) {
            #pragma unroll
            for (int r = 0; r < 4; ++r) {
                long e = e0 + mt * 16 + (lane >> 4) * 4 + r;
                if (e < n_edges) out[e] = part[r] + b3v;
            }
        }
    }
}

extern "C" void kernel_launch(void* const* d_in, const int* in_sizes, int n_in,
                              void* d_out, int out_size, void* d_ws, size_t ws_size,
                              hipStream_t stream) {
    const float* drug_feat = (const float*)d_in[0];
    const float* dis_feat  = (const float*)d_in[1];
    const int*   src_idx   = (const int*)d_in[2];
    const int*   dst_idx   = (const int*)d_in[3];
    const float* W1 = (const float*)d_in[4];
    const float* b1 = (const float*)d_in[5];
    const float* W2 = (const float*)d_in[6];
    const float* b2 = (const float*)d_in[7];
    const float* W3 = (const float*)d_in[8];
    const float* b3 = (const float*)d_in[9];
    float* out = (float*)d_out;

    int n_edges = in_sizes[2];
    int n_drug = in_sizes[0] / IN_UNITS;
    int n_dis  = in_sizes[1] / IN_UNITS;

    // ws layout: [w2pack 16KB][drug_proj][dis_proj]
    uint4* w2pack    = (uint4*)d_ws;
    float* drug_proj = (float*)((char*)d_ws + 16384);
    float* dis_proj  = drug_proj + (size_t)n_drug * H1;

    pack_w2_kernel<<<1, 256, 0, stream>>>(W2, w2pack);

    int blocks_per_side = (n_drug + 15) / 16;
    proj_kernel<<<2 * blocks_per_side, 256, 0, stream>>>(
        drug_feat, dis_feat, W1, b1, drug_proj, dis_proj, blocks_per_side);

    int edge_blocks = (n_edges + 127) / 128;
    edge_kernel<<<edge_blocks, 256, 0, stream>>>(
        drug_proj, dis_proj, src_idx, dst_idx, w2pack, b2, W3, b3, out, n_edges);
}

// Round 3
// 176.770 us; speedup vs baseline: 3.0741x; 1.3770x over previous
//
#include <hip/hip_runtime.h>
#include <hip/hip_bf16.h>

#define IN_UNITS 256
#define H1 128
#define H2 64

typedef __attribute__((ext_vector_type(8))) short bf16x8;
typedef __attribute__((ext_vector_type(4))) float f32x4;

union BV {
    uint4 u;
    __hip_bfloat162 h[4];
    bf16x8 v;
};

static __device__ __forceinline__ unsigned short bfbits(__hip_bfloat16 b) {
    union { __hip_bfloat16 b; unsigned short u; } c; c.b = b; return c.u;
}

// ---------------- K0a: pack W2 (fp32 128x64) -> bf16 MFMA B-frags ----------------
// frag f = ks*4+nt; lane l elem j = W2[ks*32 + (l>>4)*8 + j][nt*16 + (l&15)]
__global__ __launch_bounds__(256) void pack_w2_kernel(
    const float* __restrict__ W2, uint4* __restrict__ w2pack)
{
    int item = blockIdx.x * 256 + threadIdx.x;   // 0..1023
    int f = item >> 6, l = item & 63;
    int ks = f >> 2, nt = f & 3;
    int row0 = ks * 32 + (l >> 4) * 8;
    int col  = nt * 16 + (l & 15);
    unsigned short h[8];
    #pragma unroll
    for (int j = 0; j < 8; ++j)
        h[j] = bfbits(__float2bfloat16(W2[(size_t)(row0 + j) * H2 + col]));
    uint4 v;
    v.x = (unsigned)h[0] | ((unsigned)h[1] << 16);
    v.y = (unsigned)h[2] | ((unsigned)h[3] << 16);
    v.z = (unsigned)h[4] | ((unsigned)h[5] << 16);
    v.w = (unsigned)h[6] | ((unsigned)h[7] << 16);
    w2pack[item] = v;
}

// ---------------- K0b: pack W1 (fp32 512x128) -> bf16 hi/lo B-frags ----------------
// fr bits: side<<7 | ks<<4 | ntc<<1 | hl   (ntc = 0..7 col-tile of 16)
__global__ __launch_bounds__(256) void pack_w1_kernel(
    const float* __restrict__ W1, uint4* __restrict__ w1pack)
{
    int idx = blockIdx.x * 256 + threadIdx.x;   // 0..16383
    int l = idx & 63, fr = idx >> 6;            // fr 0..255
    int hl = fr & 1, ntc = (fr >> 1) & 7, ks = (fr >> 4) & 7, side = fr >> 7;
    int row0 = side * IN_UNITS + ks * 32 + (l >> 4) * 8;
    int col  = ntc * 16 + (l & 15);
    unsigned short h[8];
    #pragma unroll
    for (int j = 0; j < 8; ++j) {
        float x = W1[(size_t)(row0 + j) * H1 + col];
        __hip_bfloat16 hi = __float2bfloat16(x);
        __hip_bfloat16 val = hi;
        if (hl) val = __float2bfloat16(x - __bfloat162float(hi));
        h[j] = bfbits(val);
    }
    uint4 v;
    v.x = (unsigned)h[0] | ((unsigned)h[1] << 16);
    v.y = (unsigned)h[2] | ((unsigned)h[3] << 16);
    v.z = (unsigned)h[4] | ((unsigned)h[5] << 16);
    v.w = (unsigned)h[6] | ((unsigned)h[7] << 16);
    w1pack[idx] = v;
}

// ---------------- K1: node projections via MFMA, split-precision ----------------
// proj = feat @ W1side (+b1 on dis side), output bf16 [node][128]
// wave task: (side, 16-row m-tile, 64-col half). grid = mtiles blocks x 4 waves.
__global__ __launch_bounds__(256) void proj_kernel(
    const float* __restrict__ drug_feat, const float* __restrict__ dis_feat,
    const uint4* __restrict__ w1pack, const float* __restrict__ b1,
    unsigned short* __restrict__ drug_bf, unsigned short* __restrict__ dis_bf,
    int mtiles, int n_rows)
{
    int lane = threadIdx.x & 63, wave = threadIdx.x >> 6;
    int task = blockIdx.x * 4 + wave;
    int side = task >= 2 * mtiles;
    int t2 = task - side * 2 * mtiles;
    int mtile = t2 >> 1, ch = t2 & 1;
    const float* feat = side ? dis_feat : drug_feat;
    unsigned short* outb = side ? dis_bf : drug_bf;
    int r0 = mtile * 16;
    int kb = (lane >> 4) * 8;
    int row = r0 + (lane & 15);
    if (row >= n_rows) row = n_rows - 1;

    f32x4 acc[4];
    #pragma unroll
    for (int nt = 0; nt < 4; ++nt) acc[nt] = (f32x4){0.f, 0.f, 0.f, 0.f};

    const uint4* wp = w1pack + lane;

    #pragma unroll
    for (int ks = 0; ks < 8; ++ks) {
        const float* ap = feat + (size_t)row * IN_UNITS + ks * 32 + kb;
        float4 x0 = *(const float4*)ap;
        float4 x1 = *(const float4*)(ap + 4);
        float xs[8] = {x0.x, x0.y, x0.z, x0.w, x1.x, x1.y, x1.z, x1.w};
        BV ahi, alo;
        #pragma unroll
        for (int p = 0; p < 4; ++p) {
            float2 pr = make_float2(xs[2 * p], xs[2 * p + 1]);
            __hip_bfloat162 hp = __float22bfloat162_rn(pr);
            ahi.h[p] = hp;
            float2 lo = make_float2(xs[2 * p]     - __bfloat162float(hp.x),
                                    xs[2 * p + 1] - __bfloat162float(hp.y));
            alo.h[p] = __float22bfloat162_rn(lo);
        }
        int fbase = (side << 7) | (ks << 4) | (ch << 3);
        #pragma unroll
        for (int nt = 0; nt < 4; ++nt) {
            BV bhi, blo;
            bhi.u = wp[(size_t)((fbase | (nt << 1)) | 0) * 64];
            blo.u = wp[(size_t)((fbase | (nt << 1)) | 1) * 64];
            acc[nt] = __builtin_amdgcn_mfma_f32_16x16x32_bf16(ahi.v, bhi.v, acc[nt], 0, 0, 0);
            acc[nt] = __builtin_amdgcn_mfma_f32_16x16x32_bf16(alo.v, bhi.v, acc[nt], 0, 0, 0);
            acc[nt] = __builtin_amdgcn_mfma_f32_16x16x32_bf16(ahi.v, blo.v, acc[nt], 0, 0, 0);
        }
    }

    #pragma unroll
    for (int nt = 0; nt < 4; ++nt) {
        int col = ch * 64 + nt * 16 + (lane & 15);
        float bb = side ? b1[col] : 0.f;
        #pragma unroll
        for (int r = 0; r < 4; ++r) {
            int rr = r0 + (lane >> 4) * 4 + r;
            if (rr < n_rows)
                outb[(size_t)rr * H1 + col] = bfbits(__float2bfloat16(acc[nt][r] + bb));
        }
    }
}

// ---------------- K2: per-edge MLP via MFMA, bf16 gathers, zero LDS ----------------
__global__ __launch_bounds__(256) void edge_kernel(
    const unsigned short* __restrict__ drug_bf, const unsigned short* __restrict__ dis_bf,
    const int* __restrict__ src_idx, const int* __restrict__ dst_idx,
    const uint4* __restrict__ w2pack, const float* __restrict__ b2,
    const float* __restrict__ W3, const float* __restrict__ b3,
    float* __restrict__ out, int n_edges)
{
    int lane = threadIdx.x & 63;
    int wave = threadIdx.x >> 6;
    long e0 = ((long)blockIdx.x * 4 + wave) * 32;
    if (e0 >= n_edges) return;

    bf16x8 bfrag[4][4];
    {
        const uint4* p = w2pack + lane;
        #pragma unroll
        for (int ks = 0; ks < 4; ++ks)
            #pragma unroll
            for (int nt = 0; nt < 4; ++nt) {
                BV c; c.u = p[(size_t)(ks * 4 + nt) * 64];
                bfrag[ks][nt] = c.v;
            }
    }

    float b2v[4], w3v[4];
    #pragma unroll
    for (int nt = 0; nt < 4; ++nt) {
        int col = (lane & 15) + nt * 16;
        b2v[nt] = b2[col];
        w3v[nt] = W3[col];
    }
    float b3v = b3[0];

    f32x4 acc[2][4];
    #pragma unroll
    for (int mt = 0; mt < 2; ++mt)
        #pragma unroll
        for (int nt = 0; nt < 4; ++nt)
            acc[mt][nt] = (f32x4){0.f, 0.f, 0.f, 0.f};

    int kb = (lane >> 4) * 8;
    __hip_bfloat162 z2 = __float22bfloat162_rn(make_float2(0.f, 0.f));

    #pragma unroll
    for (int mt = 0; mt < 2; ++mt) {
        long em = e0 + mt * 16 + (lane & 15);
        if (em >= n_edges) em = n_edges - 1;
        int s = src_idx[em];
        int d = dst_idx[em];
        const uint4* dp = (const uint4*)(drug_bf + (size_t)s * H1 + kb);
        const uint4* pp = (const uint4*)(dis_bf  + (size_t)d * H1 + kb);

        bf16x8 af[4];
        #pragma unroll
        for (int ks = 0; ks < 4; ++ks) {
            BV a, c, r;
            a.u = dp[ks * 4];       // +32 bf16 per ks
            c.u = pp[ks * 4];
            #pragma unroll
            for (int j = 0; j < 4; ++j)
                r.h[j] = __hmax2(__hadd2(a.h[j], c.h[j]), z2);
            af[ks] = r.v;
        }

        #pragma unroll
        for (int ks = 0; ks < 4; ++ks)
            #pragma unroll
            for (int nt = 0; nt < 4; ++nt)
                acc[mt][nt] = __builtin_amdgcn_mfma_f32_16x16x32_bf16(
                    af[ks], bfrag[ks][nt], acc[mt][nt], 0, 0, 0);
    }

    // epilogue: out[e] = relu(h2 + b2) . W3 + b3
    // acc[mt][nt][r] = h2[edge = mt*16 + (lane>>4)*4 + r][col = (lane&15) + 16*nt]
    #pragma unroll
    for (int mt = 0; mt < 2; ++mt) {
        float part[4];
        #pragma unroll
        for (int r = 0; r < 4; ++r) {
            float p = 0.f;
            #pragma unroll
            for (int nt = 0; nt < 4; ++nt)
                p += fmaxf(acc[mt][nt][r] + b2v[nt], 0.f) * w3v[nt];
            part[r] = p;
        }
        #pragma unroll
        for (int off = 1; off <= 8; off <<= 1)
            #pragma unroll
            for (int r = 0; r < 4; ++r)
                part[r] += __shfl_xor(part[r], off, 64);
        if ((lane & 15) == 0) {
            #pragma unroll
            for (int r = 0; r < 4; ++r) {
                long e = e0 + mt * 16 + (lane >> 4) * 4 + r;
                if (e < n_edges) out[e] = part[r] + b3v;
            }
        }
    }
}

extern "C" void kernel_launch(void* const* d_in, const int* in_sizes, int n_in,
                              void* d_out, int out_size, void* d_ws, size_t ws_size,
                              hipStream_t stream) {
    const float* drug_feat = (const float*)d_in[0];
    const float* dis_feat  = (const float*)d_in[1];
    const int*   src_idx   = (const int*)d_in[2];
    const int*   dst_idx   = (const int*)d_in[3];
    const float* W1 = (const float*)d_in[4];
    const float* b1 = (const float*)d_in[5];
    const float* W2 = (const float*)d_in[6];
    const float* b2 = (const float*)d_in[7];
    const float* W3 = (const float*)d_in[8];
    const float* b3 = (const float*)d_in[9];
    float* out = (float*)d_out;

    int n_edges = in_sizes[2];
    int n_drug = in_sizes[0] / IN_UNITS;

    // ws layout: [w2pack 16KB][w1pack 256KB][drug_bf 2.56MB][dis_bf 2.56MB]
    uint4* w2pack = (uint4*)d_ws;
    uint4* w1pack = (uint4*)((char*)d_ws + 16 * 1024);
    unsigned short* drug_bf = (unsigned short*)((char*)d_ws + (16 + 256) * 1024);
    unsigned short* dis_bf  = drug_bf + (size_t)n_drug * H1;

    pack_w2_kernel<<<4, 256, 0, stream>>>(W2, w2pack);
    pack_w1_kernel<<<64, 256, 0, stream>>>(W1, w1pack);

    int mtiles = (n_drug + 15) / 16;    // 625 (n_dis == n_drug)
    proj_kernel<<<mtiles, 256, 0, stream>>>(
        drug_feat, dis_feat, w1pack, b1, drug_bf, dis_bf, mtiles, n_drug);

    int edge_blocks = (n_edges + 127) / 128;
    edge_kernel<<<edge_blocks, 256, 0, stream>>>(
        drug_bf, dis_bf, src_idx, dst_idx, w2pack, b2, W3, b3, out, n_edges);
}

// Round 4
// 166.605 us; speedup vs baseline: 3.2617x; 1.0610x over previous
//
#include <hip/hip_runtime.h>
#include <hip/hip_bf16.h>

#define IN_UNITS 256
#define H1 128
#define H2 64

typedef __attribute__((ext_vector_type(8))) short bf16x8;
typedef __attribute__((ext_vector_type(4))) float f32x4;

union BV { uint4 u; __hip_bfloat162 h[4]; bf16x8 v; };

static __device__ __forceinline__ unsigned short bfbits(__hip_bfloat16 b) {
    union { __hip_bfloat16 b; unsigned short u; } c; c.b = b; return c.u;
}

// ---------------- K0: pack W2 + W1 into bf16 MFMA B-fragment order (fused) ----
// W2 frag f = ks*4+nt: lane l elem j = W2[ks*32 + (l>>4)*8 + j][nt*16 + (l&15)]
// W1 frag fr = side<<7 | ks<<4 | ntc<<1 | hl (hi/lo split of fp32 weight)
__global__ __launch_bounds__(256) void pack_kernel(
    const float* __restrict__ W1, const float* __restrict__ W2,
    uint4* __restrict__ w1pack, uint4* __restrict__ w2pack)
{
    int b = blockIdx.x, t = threadIdx.x;
    if (b < 4) {
        int item = b * 256 + t;              // 0..1023
        int f = item >> 6, l = item & 63;
        int ks = f >> 2, nt = f & 3;
        int row0 = ks * 32 + (l >> 4) * 8;
        int col  = nt * 16 + (l & 15);
        unsigned short h[8];
        #pragma unroll
        for (int j = 0; j < 8; ++j)
            h[j] = bfbits(__float2bfloat16(W2[(size_t)(row0 + j) * H2 + col]));
        uint4 v;
        v.x = (unsigned)h[0] | ((unsigned)h[1] << 16);
        v.y = (unsigned)h[2] | ((unsigned)h[3] << 16);
        v.z = (unsigned)h[4] | ((unsigned)h[5] << 16);
        v.w = (unsigned)h[6] | ((unsigned)h[7] << 16);
        w2pack[item] = v;
    } else {
        int idx = (b - 4) * 256 + t;         // 0..16383
        int l = idx & 63, fr = idx >> 6;     // fr 0..255
        int hl = fr & 1, ntc = (fr >> 1) & 7, ks = (fr >> 4) & 7, side = fr >> 7;
        int row0 = side * IN_UNITS + ks * 32 + (l >> 4) * 8;
        int col  = ntc * 16 + (l & 15);
        unsigned short h[8];
        #pragma unroll
        for (int j = 0; j < 8; ++j) {
            float x = W1[(size_t)(row0 + j) * H1 + col];
            __hip_bfloat16 hi = __float2bfloat16(x);
            __hip_bfloat16 val = hi;
            if (hl) val = __float2bfloat16(x - __bfloat162float(hi));
            h[j] = bfbits(val);
        }
        uint4 v;
        v.x = (unsigned)h[0] | ((unsigned)h[1] << 16);
        v.y = (unsigned)h[2] | ((unsigned)h[3] << 16);
        v.z = (unsigned)h[4] | ((unsigned)h[5] << 16);
        v.w = (unsigned)h[6] | ((unsigned)h[7] << 16);
        w1pack[idx] = v;
    }
}

// ---------------- K1: node projections via MFMA + LDS-staged W1 frags --------
// block = 4 waves, all same (side, ch = 64-col half); wave w does mtile group*4+w.
// LDS holds all 64 frag-pairs for this (side,ch): 64 KB.
__global__ __launch_bounds__(256, 2) void proj_kernel(
    const float* __restrict__ drug_feat, const float* __restrict__ dis_feat,
    const uint4* __restrict__ w1pack, const float* __restrict__ b1,
    unsigned short* __restrict__ drug_bf, unsigned short* __restrict__ dis_bf,
    int n_rows)
{
    __shared__ uint4 w1s[4096];   // 64 KB: [f_loc = ks*8 + nt*2 + hl][lane]

    int t = threadIdx.x, lane = t & 63, wave = t >> 6;
    int b = blockIdx.x;
    int side = (b >> 1) & 1, ch = b & 1, group = b >> 2;

    // stage this (side,ch)'s fragments: 16 uint4 per thread, coalesced
    #pragma unroll
    for (int i = 0; i < 16; ++i) {
        int li = i * 256 + t;                // 0..4095
        int f_loc = li >> 6, l = li & 63;
        int f_glob = (side << 7) | ((f_loc >> 3) << 4) | (ch << 3) | (f_loc & 7);
        w1s[li] = w1pack[(size_t)f_glob * 64 + l];
    }
    __syncthreads();

    int mtile = group * 4 + wave;
    const float* feat = side ? dis_feat : drug_feat;
    unsigned short* outb = side ? dis_bf : drug_bf;
    int r0 = mtile * 16;
    int kb = (lane >> 4) * 8;
    int row = r0 + (lane & 15);
    if (row >= n_rows) row = n_rows - 1;

    f32x4 acc[4];
    #pragma unroll
    for (int nt = 0; nt < 4; ++nt) acc[nt] = (f32x4){0.f, 0.f, 0.f, 0.f};

    #pragma unroll
    for (int ks = 0; ks < 8; ++ks) {
        const float* ap = feat + (size_t)row * IN_UNITS + ks * 32 + kb;
        float4 x0 = *(const float4*)ap;
        float4 x1 = *(const float4*)(ap + 4);
        float xs[8] = {x0.x, x0.y, x0.z, x0.w, x1.x, x1.y, x1.z, x1.w};
        BV ahi, alo;
        #pragma unroll
        for (int p = 0; p < 4; ++p) {
            float2 pr = make_float2(xs[2 * p], xs[2 * p + 1]);
            __hip_bfloat162 hp = __float22bfloat162_rn(pr);
            ahi.h[p] = hp;
            float2 lo = make_float2(xs[2 * p]     - __bfloat162float(hp.x),
                                    xs[2 * p + 1] - __bfloat162float(hp.y));
            alo.h[p] = __float22bfloat162_rn(lo);
        }
        #pragma unroll
        for (int nt = 0; nt < 4; ++nt) {
            BV bhi, blo;
            bhi.u = w1s[(ks * 8 + nt * 2 + 0) * 64 + lane];
            blo.u = w1s[(ks * 8 + nt * 2 + 1) * 64 + lane];
            acc[nt] = __builtin_amdgcn_mfma_f32_16x16x32_bf16(ahi.v, bhi.v, acc[nt], 0, 0, 0);
            acc[nt] = __builtin_amdgcn_mfma_f32_16x16x32_bf16(alo.v, bhi.v, acc[nt], 0, 0, 0);
            acc[nt] = __builtin_amdgcn_mfma_f32_16x16x32_bf16(ahi.v, blo.v, acc[nt], 0, 0, 0);
        }
    }

    #pragma unroll
    for (int nt = 0; nt < 4; ++nt) {
        int col = ch * 64 + nt * 16 + (lane & 15);
        float bb = side ? b1[col] : 0.f;
        #pragma unroll
        for (int r = 0; r < 4; ++r) {
            int rr = r0 + (lane >> 4) * 4 + r;
            if (rr < n_rows)
                outb[(size_t)rr * H1 + col] = bfbits(__float2bfloat16(acc[nt][r] + bb));
        }
    }
}

// ---------------- K2: per-edge MLP via MFMA, LDS-staged W2, early gathers ----
// 256 threads = 4 waves; 32 edges/wave; 128 edges/block
__global__ __launch_bounds__(256, 3) void edge_kernel(
    const unsigned short* __restrict__ drug_bf, const unsigned short* __restrict__ dis_bf,
    const int* __restrict__ src_idx, const int* __restrict__ dst_idx,
    const uint4* __restrict__ w2pack, const float* __restrict__ b2,
    const float* __restrict__ W3, const float* __restrict__ b3,
    float* __restrict__ out, int n_edges)
{
    __shared__ uint4 w2s[1024];   // 16 KB: [frag = ks*4+nt][lane]

    int t = threadIdx.x, lane = t & 63, wave = t >> 6;
    long e0 = ((long)blockIdx.x * 4 + wave) * 32;
    long emax = (long)n_edges - 1;

    // 1) edge indices first
    long em0 = e0 + (lane & 15);       if (em0 > emax) em0 = emax;
    long em1 = e0 + 16 + (lane & 15);  if (em1 > emax) em1 = emax;
    int s0 = src_idx[em0], d0 = dst_idx[em0];
    int s1 = src_idx[em1], d1 = dst_idx[em1];

    // 2) issue all 16 gathers (latency hides under W2 staging + barrier)
    int kb = (lane >> 4) * 8;
    const uint4* pa0 = (const uint4*)(drug_bf + (size_t)s0 * H1 + kb);
    const uint4* pc0 = (const uint4*)(dis_bf  + (size_t)d0 * H1 + kb);
    const uint4* pa1 = (const uint4*)(drug_bf + (size_t)s1 * H1 + kb);
    const uint4* pc1 = (const uint4*)(dis_bf  + (size_t)d1 * H1 + kb);
    uint4 ga0[4], gc0[4], ga1[4], gc1[4];
    #pragma unroll
    for (int ks = 0; ks < 4; ++ks) {
        ga0[ks] = pa0[ks * 4];
        gc0[ks] = pc0[ks * 4];
        ga1[ks] = pa1[ks * 4];
        gc1[ks] = pc1[ks * 4];
    }

    // 3) stage W2 frags to LDS (4 uint4/thread, coalesced)
    #pragma unroll
    for (int i = 0; i < 4; ++i) w2s[i * 256 + t] = w2pack[i * 256 + t];
    __syncthreads();

    // epilogue constants
    float b2v[4], w3v[4];
    #pragma unroll
    for (int nt = 0; nt < 4; ++nt) {
        int col = (lane & 15) + nt * 16;
        b2v[nt] = b2[col];
        w3v[nt] = W3[col];
    }
    float b3v = b3[0];

    f32x4 acc[2][4];
    #pragma unroll
    for (int mt = 0; mt < 2; ++mt)
        #pragma unroll
        for (int nt = 0; nt < 4; ++nt)
            acc[mt][nt] = (f32x4){0.f, 0.f, 0.f, 0.f};

    __hip_bfloat162 z2 = __float22bfloat162_rn(make_float2(0.f, 0.f));

    #pragma unroll
    for (int ks = 0; ks < 4; ++ks) {
        BV a0, c0, a1, c1, r0v, r1v;
        a0.u = ga0[ks]; c0.u = gc0[ks];
        a1.u = ga1[ks]; c1.u = gc1[ks];
        #pragma unroll
        for (int j = 0; j < 4; ++j) {
            r0v.h[j] = __hmax2(__hadd2(a0.h[j], c0.h[j]), z2);
            r1v.h[j] = __hmax2(__hadd2(a1.h[j], c1.h[j]), z2);
        }
        #pragma unroll
        for (int nt = 0; nt < 4; ++nt) {
            BV bb; bb.u = w2s[(ks * 4 + nt) * 64 + lane];
            acc[0][nt] = __builtin_amdgcn_mfma_f32_16x16x32_bf16(r0v.v, bb.v, acc[0][nt], 0, 0, 0);
            acc[1][nt] = __builtin_amdgcn_mfma_f32_16x16x32_bf16(r1v.v, bb.v, acc[1][nt], 0, 0, 0);
        }
    }

    // epilogue: out[e] = relu(h2 + b2) . W3 + b3
    // acc[mt][nt][r] = h2[edge = mt*16 + (lane>>4)*4 + r][col = (lane&15) + 16*nt]
    #pragma unroll
    for (int mt = 0; mt < 2; ++mt) {
        float part[4];
        #pragma unroll
        for (int r = 0; r < 4; ++r) {
            float p = 0.f;
            #pragma unroll
            for (int nt = 0; nt < 4; ++nt)
                p += fmaxf(acc[mt][nt][r] + b2v[nt], 0.f) * w3v[nt];
            part[r] = p;
        }
        #pragma unroll
        for (int off = 1; off <= 8; off <<= 1)
            #pragma unroll
            for (int r = 0; r < 4; ++r)
                part[r] += __shfl_xor(part[r], off, 64);
        if ((lane & 15) == 0) {
            #pragma unroll
            for (int r = 0; r < 4; ++r) {
                long e = e0 + mt * 16 + (lane >> 4) * 4 + r;
                if (e < n_edges) out[e] = part[r] + b3v;
            }
        }
    }
}

extern "C" void kernel_launch(void* const* d_in, const int* in_sizes, int n_in,
                              void* d_out, int out_size, void* d_ws, size_t ws_size,
                              hipStream_t stream) {
    const float* drug_feat = (const float*)d_in[0];
    const float* dis_feat  = (const float*)d_in[1];
    const int*   src_idx   = (const int*)d_in[2];
    const int*   dst_idx   = (const int*)d_in[3];
    const float* W1 = (const float*)d_in[4];
    const float* b1 = (const float*)d_in[5];
    const float* W2 = (const float*)d_in[6];
    const float* b2 = (const float*)d_in[7];
    const float* W3 = (const float*)d_in[8];
    const float* b3 = (const float*)d_in[9];
    float* out = (float*)d_out;

    int n_edges = in_sizes[2];
    int n_drug = in_sizes[0] / IN_UNITS;

    // ws layout: [w2pack 16KB][w1pack 256KB][drug_bf 2.56MB][dis_bf 2.56MB]
    uint4* w2pack = (uint4*)d_ws;
    uint4* w1pack = (uint4*)((char*)d_ws + 16 * 1024);
    unsigned short* drug_bf = (unsigned short*)((char*)d_ws + (16 + 256) * 1024);
    unsigned short* dis_bf  = drug_bf + (size_t)n_drug * H1;

    pack_kernel<<<68, 256, 0, stream>>>(W1, W2, w1pack, w2pack);

    int groups = (((n_drug + 15) / 16) + 3) / 4;    // 157
    proj_kernel<<<groups * 4, 256, 0, stream>>>(
        drug_feat, dis_feat, w1pack, b1, drug_bf, dis_bf, n_drug);

    int edge_blocks = (n_edges + 127) / 128;        // 7813
    edge_kernel<<<edge_blocks, 256, 0, stream>>>(
        drug_bf, dis_bf, src_idx, dst_idx, w2pack, b2, W3, b3, out, n_edges);
}